// Round 5
// baseline (288.115 us; speedup 1.0000x reference)
//
#include <hip/hip_runtime.h>
#include <hip/hip_bf16.h>

#define N_NODES 50000
#define N_EDGES 800000
#define DIN     128
#define HD      128   // H * D_HEAD
#define NHEAD   8
#define DHEAD   16

#define M_PAD        50176           // 1024 * 49, scan-padded node count
#define HIST_BLOCKS  3125            // ceil(800000/256)
#define CVTW_BLOCKS  192             // 3*128*128/256
#define PROJ_PM      391             // proj blocks per matrix (128 rows each)
#define PROJ_BLOCKS  (PROJ_PM * 3)   // 1173
#define SCAT_BLOCKS  1563            // ceil(800000/512), 2 edges/thread

typedef __attribute__((ext_vector_type(8))) short short8;   // 8 bf16
typedef __attribute__((ext_vector_type(4))) float float4v;  // 4 fp32 acc

static __device__ __forceinline__ unsigned short f2bf_bits(float f) {
    __hip_bfloat16 b = __float2bfloat16(f);
    return *reinterpret_cast<unsigned short*>(&b);
}
static __device__ __forceinline__ float bfb(short b) {
    return __uint_as_float(((unsigned int)(unsigned short)b) << 16);
}
static __device__ __forceinline__ short8 cvt8(const float* p) {
    const float4 f0 = *(const float4*)p;
    const float4 f1 = *(const float4*)(p + 4);
    short8 r;
    r[0] = (short)f2bf_bits(f0.x); r[1] = (short)f2bf_bits(f0.y);
    r[2] = (short)f2bf_bits(f0.z); r[3] = (short)f2bf_bits(f0.w);
    r[4] = (short)f2bf_bits(f1.x); r[5] = (short)f2bf_bits(f1.y);
    r[6] = (short)f2bf_bits(f1.z); r[7] = (short)f2bf_bits(f1.w);
    return r;
}

// ---------------------------------------------------------------------------
// Node 2: dst-histogram  +  W transpose/convert (independent work, one launch)
// ---------------------------------------------------------------------------
__global__ __launch_bounds__(256) void hist_cvtw_kernel(
    const int* __restrict__ dst,
    const float* __restrict__ Wq, const float* __restrict__ Wk,
    const float* __restrict__ Wv,
    int* __restrict__ counts, unsigned short* __restrict__ Wt)
{
    const int bid = blockIdx.x;
    if (bid < HIST_BLOCKS) {
        const int e = bid * 256 + threadIdx.x;
        if (e < N_EDGES) atomicAdd(&counts[dst[e]], 1);
    } else {
        const int i   = (bid - HIST_BLOCKS) * 256 + threadIdx.x; // < 49152
        const int n   = i & 127;
        const int k   = (i >> 7) & 127;
        const int mat = i >> 14;
        const float* W = (mat == 0) ? Wq : (mat == 1) ? Wk : Wv;
        Wt[mat * (DIN * HD) + n * DIN + k] = f2bf_bits(W[k * HD + n]);
    }
}

// ---------------------------------------------------------------------------
// Node 3: full exclusive scan of counts[0..50175] in ONE block.
// Thread t owns the contiguous range [t*49, t*49+49).
// ---------------------------------------------------------------------------
__global__ __launch_bounds__(1024) void scan_kernel(
    const int* __restrict__ counts, int* __restrict__ cursor)
{
    __shared__ int s[1024];
    const int tid  = threadIdx.x;
    const int base = tid * 49;

    int sum = 0;
    #pragma unroll
    for (int i = 0; i < 49; ++i) sum += counts[base + i];

    s[tid] = sum;
    __syncthreads();
    for (int off = 1; off < 1024; off <<= 1) {
        int x = (tid >= off) ? s[tid - off] : 0;
        __syncthreads();
        s[tid] += x;
        __syncthreads();
    }
    int excl = s[tid] - sum;
    #pragma unroll
    for (int i = 0; i < 49; ++i) {
        cursor[base + i] = excl;
        excl += counts[base + i];
    }
}

// ---------------------------------------------------------------------------
// Node 4: fused  [Q/K/V projection via bf16 MFMA]  +  [edge scatter sort].
// proj: blocks [0, PROJ_BLOCKS): one MATRIX (Q, K, or V) x 128 rows per
//       block -> 1173 blocks (~4.6/CU) for latency hiding.  A-fragments
//       (h rows) converted fp32->bf16 in-register; Wt (32 KB/mat) L1-hot.
// scatter: blocks [PROJ_BLOCKS, ...): 2 edges per thread (2 independent
//       atomic->store chains for MLP).  After this kernel
//       cursor[n] == row END of node n.
// ---------------------------------------------------------------------------
__global__ __launch_bounds__(256) void proj_scatter_kernel(
    const float* __restrict__ h,
    const unsigned short* __restrict__ Wt,
    const float* __restrict__ bq, const float* __restrict__ bk,
    const float* __restrict__ bv,
    const int* __restrict__ src, const int* __restrict__ dst,
    int* __restrict__ cursor,
    float* __restrict__ Qf, __hip_bfloat16* __restrict__ KV,
    int* __restrict__ sorted_src)
{
    const int bid = blockIdx.x;
    if (bid >= PROJ_BLOCKS) {
        const int e0 = (bid - PROJ_BLOCKS) * 512 + threadIdx.x;
        const int e1 = e0 + 256;
        // two independent atomic->store chains per thread
        int d0 = -1, d1 = -1, v0 = 0, v1 = 0;
        if (e0 < N_EDGES) { d0 = dst[e0]; v0 = src[e0]; }
        if (e1 < N_EDGES) { d1 = dst[e1]; v1 = src[e1]; }
        if (d0 >= 0) {
            const int p0 = atomicAdd(&cursor[d0], 1);
            sorted_src[p0] = v0;
        }
        if (d1 >= 0) {
            const int p1 = atomicAdd(&cursor[d1], 1);
            sorted_src[p1] = v1;
        }
        return;
    }

    const int mat  = bid / PROJ_PM;            // 0=Q, 1=K, 2=V
    const int rblk = bid % PROJ_PM;
    const int wave = threadIdx.x >> 6;
    const int lane = threadIdx.x & 63;
    const int quad = lane >> 4;
    const int l16  = lane & 15;
    const int rowBase = rblk * 128 + wave * 32;

    int r0 = rowBase + l16;       if (r0 >= N_NODES) r0 = N_NODES - 1;
    int r1 = rowBase + 16 + l16;  if (r1 >= N_NODES) r1 = N_NODES - 1;

    // A fragments: load h rows (fp32), convert to bf16 in-register.
    short8 afr[2][4];
    #pragma unroll
    for (int kc = 0; kc < 4; ++kc) {
        const int ko = kc * 32 + quad * 8;
        afr[0][kc] = cvt8(h + (size_t)r0 * DIN + ko);
        afr[1][kc] = cvt8(h + (size_t)r1 * DIN + ko);
    }

    const unsigned short* wb = Wt + mat * (DIN * HD);
    const float* bias = (mat == 0) ? bq : (mat == 1) ? bk : bv;

    float4v acc[2][8];
    #pragma unroll
    for (int rt = 0; rt < 2; ++rt)
        #pragma unroll
        for (int ct = 0; ct < 8; ++ct)
            acc[rt][ct] = (float4v){0.f, 0.f, 0.f, 0.f};

    #pragma unroll
    for (int kc = 0; kc < 4; ++kc) {
        const int ko = kc * 32 + quad * 8;
        #pragma unroll
        for (int ct = 0; ct < 8; ++ct) {
            const short8 b = *(const short8*)(wb + (ct * 16 + l16) * DIN + ko);
            acc[0][ct] = __builtin_amdgcn_mfma_f32_16x16x32_bf16(afr[0][kc], b, acc[0][ct], 0, 0, 0);
            acc[1][ct] = __builtin_amdgcn_mfma_f32_16x16x32_bf16(afr[1][kc], b, acc[1][ct], 0, 0, 0);
        }
    }

    #pragma unroll
    for (int ct = 0; ct < 8; ++ct) {
        const int col = ct * 16 + l16;
        const float bcol = bias[col];
        #pragma unroll
        for (int rt = 0; rt < 2; ++rt) {
            #pragma unroll
            for (int r = 0; r < 4; ++r) {
                const int row = rowBase + rt * 16 + quad * 4 + r;
                if (row < N_NODES) {
                    const float v = acc[rt][ct][r] + bcol;
                    if (mat == 0)
                        Qf[(size_t)row * HD + col] = v;
                    else
                        KV[(size_t)row * 256 + (mat == 2 ? 128 : 0) + col] =
                            __float2bfloat16(v);
                }
            }
        }
    }
}

// ---------------------------------------------------------------------------
// Node 5: aggregate.  One 128-thread block per destination node; edges in
// batches of 16.  Phase A: thread=(edge j, head h) computes the 16-elem dot
// ONCE (fp32 Q in registers, bf16 K gather), one exp per score -> LDS.
// Phase B: thread=(h,d) does V-gather fma with LDS score broadcast.
// ---------------------------------------------------------------------------
__global__ __launch_bounds__(128) void aggregate_kernel(
    const float* __restrict__ Qf, const __hip_bfloat16* __restrict__ KV,
    const int* __restrict__ cursor, const int* __restrict__ counts,
    const int* __restrict__ sorted_src, float* __restrict__ out)
{
    const int node = blockIdx.x;
    const int t    = threadIdx.x;
    const int end  = cursor[node];
    const int beg  = end - counts[node];

    const int jA = t >> 3;     // edge slot in batch (0..15)
    const int hA = t & 7;      // head for phase A
    const int hB = t >> 4;     // head for phase B

    __shared__ float sc_s[16][8];
    __shared__ int   s_s[16];

    const float* qseg = Qf + (size_t)node * HD + hA * 16;
    const float4 q0 = *(const float4*)(qseg);
    const float4 q1 = *(const float4*)(qseg + 4);
    const float4 q2 = *(const float4*)(qseg + 8);
    const float4 q3 = *(const float4*)(qseg + 12);

    const short* kvb   = (const short*)KV;
    const short* vbase = kvb + 128 + t;

    float acc = 0.f, zacc = 0.f;

    for (int e0 = beg; e0 < end; e0 += 16) {
        const int nb = min(16, end - e0);

        if (jA < nb) {
            const int s = sorted_src[e0 + jA];
            if (hA == 0) s_s[jA] = s;
            const short* kp = kvb + (size_t)s * 256 + hA * 16;
            const short8 k0 = *(const short8*)kp;
            const short8 k1 = *(const short8*)(kp + 8);
            float dot;
            dot  = q0.x * bfb(k0[0]) + q0.y * bfb(k0[1])
                 + q0.z * bfb(k0[2]) + q0.w * bfb(k0[3]);
            dot += q1.x * bfb(k0[4]) + q1.y * bfb(k0[5])
                 + q1.z * bfb(k0[6]) + q1.w * bfb(k0[7]);
            dot += q2.x * bfb(k1[0]) + q2.y * bfb(k1[1])
                 + q2.z * bfb(k1[2]) + q2.w * bfb(k1[3]);
            dot += q3.x * bfb(k1[4]) + q3.y * bfb(k1[5])
                 + q3.z * bfb(k1[6]) + q3.w * bfb(k1[7]);
            sc_s[jA][hA] = __expf(fminf(fmaxf(dot * 0.25f, -5.f), 5.f));
        }
        __syncthreads();

        int j = 0;
        for (; j + 3 < nb; j += 4) {
            const int s0 = s_s[j],     s1 = s_s[j + 1];
            const int s2 = s_s[j + 2], s3 = s_s[j + 3];
            const float c0 = sc_s[j][hB],     c1 = sc_s[j + 1][hB];
            const float c2 = sc_s[j + 2][hB], c3 = sc_s[j + 3][hB];
            const float v0 = bfb(vbase[(size_t)s0 * 256]);
            const float v1 = bfb(vbase[(size_t)s1 * 256]);
            const float v2 = bfb(vbase[(size_t)s2 * 256]);
            const float v3 = bfb(vbase[(size_t)s3 * 256]);
            acc = fmaf(v0, c0, acc); acc = fmaf(v1, c1, acc);
            acc = fmaf(v2, c2, acc); acc = fmaf(v3, c3, acc);
            zacc += (c0 + c1) + (c2 + c3);
        }
        for (; j < nb; ++j) {
            const int s0 = s_s[j];
            const float c0 = sc_s[j][hB];
            acc = fmaf(bfb(vbase[(size_t)s0 * 256]), c0, acc);
            zacc += c0;
        }
        __syncthreads();
    }

    out[(size_t)node * HD + t] = acc / (zacc + 1e-6f);
}

// ---------------------------------------------------------------------------
extern "C" void kernel_launch(void* const* d_in, const int* in_sizes, int n_in,
                              void* d_out, int out_size, void* d_ws, size_t ws_size,
                              hipStream_t stream)
{
    const float* h   = (const float*)d_in[0];
    const float* Wq  = (const float*)d_in[1];
    const float* bq  = (const float*)d_in[2];
    const float* Wk  = (const float*)d_in[3];
    const float* bk  = (const float*)d_in[4];
    const float* Wv  = (const float*)d_in[5];
    const float* bv  = (const float*)d_in[6];
    const int*   src = (const int*)d_in[7];
    const int*   dst = (const int*)d_in[8];
    float* out = (float*)d_out;

    // workspace layout (16B-aligned segments):
    //   Qf fp32 [50000][128]            25.6 MB
    //   KV bf16 [50000][K128|V128]      25.6 MB
    //   Wt bf16 [3][128][128]            0.1 MB
    //   counts / cursor int [50176]      0.4 MB
    //   sorted_src int [800000]          3.2 MB
    float* Qf = (float*)d_ws;
    __hip_bfloat16* KV = (__hip_bfloat16*)(Qf + (size_t)N_NODES * HD);
    unsigned short* Wt = (unsigned short*)(KV + (size_t)N_NODES * 256);
    int* counts     = (int*)(Wt + 3 * DIN * HD);
    int* cursor     = counts + M_PAD;
    int* sorted_src = cursor + M_PAD;

    hipMemsetAsync(counts, 0, M_PAD * sizeof(int), stream);

    hist_cvtw_kernel<<<HIST_BLOCKS + CVTW_BLOCKS, 256, 0, stream>>>(
        dst, Wq, Wk, Wv, counts, Wt);

    scan_kernel<<<1, 1024, 0, stream>>>(counts, cursor);

    proj_scatter_kernel<<<PROJ_BLOCKS + SCAT_BLOCKS, 256, 0, stream>>>(
        h, Wt, bq, bk, bv, src, dst, cursor, Qf, KV, sorted_src);

    aggregate_kernel<<<N_NODES, 128, 0, stream>>>(
        Qf, KV, cursor, counts, sorted_src, out);
}